// Round 2
// baseline (498.528 us; speedup 1.0000x reference)
//
#include <hip/hip_runtime.h>
#include <hip/hip_bf16.h>

// Problem constants (reference: IN_F=4096, OUT_F=4096, GROUP=128, x = (4,2048,4096))
#define K_DIM 4096
#define N_DIM 4096
#define M_DIM 8192
#define NT 64                       // K_DIM / 64 K-tiles

typedef __bf16 bf16x8 __attribute__((ext_vector_type(8)));
typedef float floatx4 __attribute__((ext_vector_type(4)));

__device__ __forceinline__ unsigned short f2bf(float f) {
    union { float f; unsigned u; } v; v.f = f;
    unsigned u = v.u;
    return (unsigned short)((u + 0x7FFFu + ((u >> 16) & 1u)) >> 16);  // RNE
}

// ---------------- kernel 1: cast x (fp32 -> bf16), 8 elems/thread ----------------
__global__ __launch_bounds__(256) void cast_x_kernel(const float* __restrict__ x,
                                                     unsigned short* __restrict__ xb) {
    const int t = blockIdx.x * 256 + threadIdx.x;
    const int base = t * 8;
    float4 f0 = *(const float4*)(x + base);
    float4 f1 = *(const float4*)(x + base + 4);
    int4 o;
    o.x = (int)f2bf(f0.x) | ((int)f2bf(f0.y) << 16);
    o.y = (int)f2bf(f0.z) | ((int)f2bf(f0.w) << 16);
    o.z = (int)f2bf(f1.x) | ((int)f2bf(f1.y) << 16);
    o.w = (int)f2bf(f1.z) | ((int)f2bf(f1.w) << 16);
    *(int4*)(xb + base) = o;
}

// ------------- kernel 2: dequant int4 -> bf16 W^T (N x K, k contiguous), LDS transpose -------------
__global__ __launch_bounds__(256) void dequant_kernel(const int* __restrict__ qw,
                                                      const float* __restrict__ scales,
                                                      const float* __restrict__ zeros,
                                                      unsigned short* __restrict__ wt) {
    __shared__ int4 lds[128 * 8];                   // [n][chunk], 16 KB
    const int tid = threadIdx.x;
    const int nb = (blockIdx.x & 31) * 128;         // n-block base
    const int kb = blockIdx.x >> 5;                 // 0..63, k0 = kb*64
    const int p0 = kb * 8;                          // packed-row base (8 words = 64 k)
    const int g = kb >> 1;                          // quant group (uniform per block)

#pragma unroll
    for (int it = 0; it < 4; ++it) {
        const int w = tid + it * 256;               // 0..1023
        const int p = w >> 7;                       // 0..7
        const int n = w & 127;
        const unsigned word = (unsigned)qw[(p0 + p) * N_DIM + nb + n];
        const float s = scales[g * N_DIM + nb + n];
        const float z = zeros[g * N_DIM + nb + n];
        unsigned short h[8];
#pragma unroll
        for (int j = 0; j < 8; ++j) {
            float q = (float)((word >> (4 * j)) & 0xFu);
            h[j] = f2bf(q * s - z);
        }
        int4 o;
        o.x = (int)h[0] | ((int)h[1] << 16);
        o.y = (int)h[2] | ((int)h[3] << 16);
        o.z = (int)h[4] | ((int)h[5] << 16);
        o.w = (int)h[6] | ((int)h[7] << 16);
        lds[n * 8 + (p ^ (n & 7))] = o;             // swizzled chunk
    }
    __syncthreads();

#pragma unroll
    for (int it = 0; it < 4; ++it) {
        const int r = (tid >> 3) + it * 32;         // n-row 0..127
        const int oc = tid & 7;                     // k-chunk 0..7
        int4 v = lds[r * 8 + (oc ^ (r & 7))];
        *(int4*)(wt + (size_t)(nb + r) * K_DIM + kb * 64 + oc * 8) = v;
    }
}

// ------------- kernel 3: bf16 GEMM, 256x256 tile, BK=64, balanced-phase counted-vmcnt pipeline -----
// A = xb (M x K), B = wt (N x K), C = out (M x N fp32) + bias.
// 8 waves (2M x 4N), each owns 128x64 of C: acc[8][4] f32x4. LDS 128 KiB double-buffered.
// Chunk-XOR swizzle: linear gload_lds dest + pre-swizzled global src; frag reads un-swizzle
// (2 lanes/chunk, verified 0 bank conflicts).
//
// R2 change: m201-style balanced read distribution + per-phase lgkm(0) gating AFTER the
// rendezvous barrier (wave-skew overlap of LDS reads with MFMA). Reads per phase 12/4/8/0
// (was 16/0/8/0 with a pre-barrier lgkm(8) that serialized all waves on the LDS queue).
//  P1: read aL(8)+b-lo(4); stage (t+1).A1->obuf; bar; lgkm0; MFMA Q1=Mlo*Nlo; bar
//  P2: read b-hi(4);                              bar; lgkm0; MFMA Q2=Mlo*Nhi; bar
//  P3: read aH(8, reuse aL regs); stage (t+2).B0->buf; bar; lgkm0; MFMA Q3=Mhi*Nhi; bar
//  P4: stage (t+2).B1,A0->buf; bar; MFMA Q4=Mhi*Nlo; vmcnt(6); bar
// Safety: every phase's reads complete at its lgkm(0) gate, so by each phase-end barrier the
// regions staged next are fully read (B done by P2-end -> B0@P3, B1@P4; A done by P3-end ->
// A0@P4; obuf's A1 region last read in tile t-1 P3). vmcnt(6) at P4-end (before the barrier!)
// leaves exactly the 3 (t+2) half-tiles in flight => tile t+1 landed for all waves after the
// barrier. Tail: vmcnt(0) when t+2>=NT.
__device__ __forceinline__ void gl_lds16(const unsigned short* g, unsigned short* l) {
    __builtin_amdgcn_global_load_lds((__attribute__((address_space(1))) void*)g,
                                     (__attribute__((address_space(3))) void*)l, 16, 0, 0);
}

__global__ __launch_bounds__(512, 2) void gemm_kernel(const unsigned short* __restrict__ A,
                                                      const unsigned short* __restrict__ B,
                                                      const float* __restrict__ bias,
                                                      float* __restrict__ C) {
    __shared__ unsigned short As[2 * 256 * 64];     // 64 KB
    __shared__ unsigned short Bs[2 * 256 * 64];     // 64 KB

    const int tid = threadIdx.x;
    const int lane = tid & 63;
    const int wave = tid >> 6;

    // XCD-aware swizzle (512 blocks, 512 % 8 == 0 -> bijective)
    int bid = blockIdx.x;
    bid = (bid & 7) * 64 + (bid >> 3);
    const int tileM = (bid >> 4) * 256;
    const int tileN = (bid & 15) * 256;

    const int m0 = (wave >> 2) * 128;               // wave's M offset within tile
    const int n0 = (wave & 3) * 64;                 // wave's N offset within tile
    const int frow = lane & 15;
    const int fkq = lane >> 4;                      // k-chunk quarter
    const int sw = frow & 7;
    const int ch0 = (fkq ^ sw) << 3;                // kh=0 un-swizzled elem offset
    const int ch1 = ((fkq ^ sw) ^ 4) << 3;          // kh=1

    // staging geometry: thread covers one 16B chunk per half-tile load
    const int r0 = tid >> 3;                        // 0..63
    const int kcg = (tid & 7) ^ (r0 & 7);
    const int dst0 = tid * 8;                       // elem offset in half (load 0); load 1: +4096

    const unsigned short* Abase = A + (size_t)(tileM + r0) * K_DIM + kcg * 8;
    const unsigned short* Bbase = B + (size_t)(tileN + r0) * K_DIM + kcg * 8;

#define STAGE_A(T, H, BUF) do {                                                        \
        const unsigned short* _s = Abase + (size_t)(H) * (128 * K_DIM) + (T) * 64;     \
        gl_lds16(_s, &As[((BUF) << 14) + ((H) << 13) + dst0]);                         \
        gl_lds16(_s + 64 * K_DIM, &As[((BUF) << 14) + ((H) << 13) + 4096 + dst0]);     \
    } while (0)
#define STAGE_B(T, H, BUF) do {                                                        \
        const unsigned short* _s = Bbase + (size_t)(H) * (128 * K_DIM) + (T) * 64;     \
        gl_lds16(_s, &Bs[((BUF) << 14) + ((H) << 13) + dst0]);                         \
        gl_lds16(_s + 64 * K_DIM, &Bs[((BUF) << 14) + ((H) << 13) + 4096 + dst0]);     \
    } while (0)

    floatx4 acc[8][4];
#pragma unroll
    for (int i = 0; i < 8; ++i)
#pragma unroll
        for (int j = 0; j < 4; ++j) acc[i][j] = (floatx4){0.f, 0.f, 0.f, 0.f};

    // prologue: tile0 {B0,B1,A0,A1} -> buf0; tile1 {B0,B1,A0} -> buf1 (7 halves = 14 loads/wave)
    STAGE_B(0, 0, 0); STAGE_B(0, 1, 0); STAGE_A(0, 0, 0); STAGE_A(0, 1, 0);
    STAGE_B(1, 0, 1); STAGE_B(1, 1, 1); STAGE_A(1, 0, 1);
    asm volatile("s_waitcnt vmcnt(6)" ::: "memory");    // tile0's 4 halves retired (in-order)
    __builtin_amdgcn_s_barrier();

    bf16x8 a[4][2], b[4][2];

#pragma unroll 2
    for (int t = 0; t < NT; ++t) {
        const int buf = t & 1;
        const int bo = buf << 14;

        // ---- P1: read aL(8) + b-lo(4); stage (t+1).A1 -> other buf; MFMA Q1 = Mlo x Nlo
#pragma unroll
        for (int mi = 0; mi < 4; ++mi) {
            const int row = m0 + mi * 16 + frow;
            a[mi][0] = *(const bf16x8*)&As[bo + row * 64 + ch0];
            a[mi][1] = *(const bf16x8*)&As[bo + row * 64 + ch1];
        }
#pragma unroll
        for (int ni = 0; ni < 2; ++ni) {
            const int row = n0 + ni * 16 + frow;
            b[ni][0] = *(const bf16x8*)&Bs[bo + row * 64 + ch0];
            b[ni][1] = *(const bf16x8*)&Bs[bo + row * 64 + ch1];
        }
        if (t + 1 < NT) STAGE_A(t + 1, 1, buf ^ 1);
        __builtin_amdgcn_s_barrier();
        asm volatile("s_waitcnt lgkmcnt(0)" ::: "memory");
        __builtin_amdgcn_sched_barrier(0);
        __builtin_amdgcn_s_setprio(1);
#pragma unroll
        for (int mi = 0; mi < 4; ++mi)
#pragma unroll
            for (int ni = 0; ni < 2; ++ni)
#pragma unroll
                for (int kh = 0; kh < 2; ++kh)
                    acc[mi][ni] = __builtin_amdgcn_mfma_f32_16x16x32_bf16(
                        a[mi][kh], b[ni][kh], acc[mi][ni], 0, 0, 0);
        __builtin_amdgcn_s_setprio(0);
        __builtin_amdgcn_sched_barrier(0);
        __builtin_amdgcn_s_barrier();

        // ---- P2: read b-hi(4); MFMA Q2 = Mlo x Nhi
#pragma unroll
        for (int ni = 2; ni < 4; ++ni) {
            const int row = n0 + ni * 16 + frow;
            b[ni][0] = *(const bf16x8*)&Bs[bo + row * 64 + ch0];
            b[ni][1] = *(const bf16x8*)&Bs[bo + row * 64 + ch1];
        }
        __builtin_amdgcn_s_barrier();
        asm volatile("s_waitcnt lgkmcnt(0)" ::: "memory");
        __builtin_amdgcn_sched_barrier(0);
        __builtin_amdgcn_s_setprio(1);
#pragma unroll
        for (int mi = 0; mi < 4; ++mi)
#pragma unroll
            for (int ni = 2; ni < 4; ++ni)
#pragma unroll
                for (int kh = 0; kh < 2; ++kh)
                    acc[mi][ni] = __builtin_amdgcn_mfma_f32_16x16x32_bf16(
                        a[mi][kh], b[ni][kh], acc[mi][ni], 0, 0, 0);
        __builtin_amdgcn_s_setprio(0);
        __builtin_amdgcn_sched_barrier(0);
        __builtin_amdgcn_s_barrier();

        // ---- P3: read aH(8, reuse a[] regs); stage (t+2).B0 -> this buf; MFMA Q3 = Mhi x Nhi
#pragma unroll
        for (int mi = 0; mi < 4; ++mi) {
            const int row = m0 + 64 + mi * 16 + frow;
            a[mi][0] = *(const bf16x8*)&As[bo + row * 64 + ch0];
            a[mi][1] = *(const bf16x8*)&As[bo + row * 64 + ch1];
        }
        if (t + 2 < NT) STAGE_B(t + 2, 0, buf);
        __builtin_amdgcn_s_barrier();
        asm volatile("s_waitcnt lgkmcnt(0)" ::: "memory");
        __builtin_amdgcn_sched_barrier(0);
        __builtin_amdgcn_s_setprio(1);
#pragma unroll
        for (int mi = 0; mi < 4; ++mi)
#pragma unroll
            for (int ni = 2; ni < 4; ++ni)
#pragma unroll
                for (int kh = 0; kh < 2; ++kh)
                    acc[4 + mi][ni] = __builtin_amdgcn_mfma_f32_16x16x32_bf16(
                        a[mi][kh], b[ni][kh], acc[4 + mi][ni], 0, 0, 0);
        __builtin_amdgcn_s_setprio(0);
        __builtin_amdgcn_sched_barrier(0);
        __builtin_amdgcn_s_barrier();

        // ---- P4: stage (t+2).B1,A0 -> this buf; MFMA Q4 = Mhi x Nlo; counted vmcnt drain
        if (t + 2 < NT) { STAGE_B(t + 2, 1, buf); STAGE_A(t + 2, 0, buf); }
        __builtin_amdgcn_s_barrier();
        __builtin_amdgcn_sched_barrier(0);
        __builtin_amdgcn_s_setprio(1);
#pragma unroll
        for (int mi = 0; mi < 4; ++mi)
#pragma unroll
            for (int ni = 0; ni < 2; ++ni)
#pragma unroll
                for (int kh = 0; kh < 2; ++kh)
                    acc[4 + mi][ni] = __builtin_amdgcn_mfma_f32_16x16x32_bf16(
                        a[mi][kh], b[ni][kh], acc[4 + mi][ni], 0, 0, 0);
        __builtin_amdgcn_s_setprio(0);
        // counted drain: 3 half-tiles (t+2) stay in flight; tile t+1 guaranteed landed for all
        // waves after the following barrier.
        if (t + 2 < NT) { asm volatile("s_waitcnt vmcnt(6)" ::: "memory"); }
        else            { asm volatile("s_waitcnt vmcnt(0)" ::: "memory"); }
        __builtin_amdgcn_sched_barrier(0);
        __builtin_amdgcn_s_barrier();
    }
#undef STAGE_A
#undef STAGE_B

    // no pending LDS-DMA may outlive the kernel
    asm volatile("s_waitcnt vmcnt(0)" ::: "memory");

    // epilogue: C/D layout col = lane&15, row = (lane>>4)*4 + reg
    const int crow = (lane >> 4) * 4;
    const int ccol = lane & 15;
#pragma unroll
    for (int ni = 0; ni < 4; ++ni) {
        const int gcol = tileN + n0 + ni * 16 + ccol;
        const float bv = bias[gcol];
#pragma unroll
        for (int mi = 0; mi < 8; ++mi) {
            const int rbase = (tileM + m0 + mi * 16 + crow) * N_DIM + gcol;
#pragma unroll
            for (int r = 0; r < 4; ++r)
                C[rbase + r * N_DIM] = acc[mi][ni][r] + bv;
        }
    }
}

extern "C" void kernel_launch(void* const* d_in, const int* in_sizes, int n_in,
                              void* d_out, int out_size, void* d_ws, size_t ws_size,
                              hipStream_t stream) {
    (void)in_sizes; (void)n_in; (void)out_size; (void)ws_size;
    const float* x      = (const float*)d_in[0];
    const int*   qw     = (const int*)d_in[1];
    const float* scales = (const float*)d_in[2];
    const float* zeros  = (const float*)d_in[3];
    const float* bias   = (const float*)d_in[4];
    float* out = (float*)d_out;

    unsigned short* xb = (unsigned short*)d_ws;                      // 8192*4096 bf16 = 64 MiB
    unsigned short* wt = xb + (size_t)M_DIM * K_DIM;                 // 4096*4096 bf16 = 32 MiB

    hipLaunchKernelGGL(cast_x_kernel, dim3(16384), dim3(256), 0, stream, x, xb);
    hipLaunchKernelGGL(dequant_kernel, dim3(2048), dim3(256), 0, stream, qw, scales, zeros, wt);
    hipLaunchKernelGGL(gemm_kernel, dim3(512), dim3(512), 0, stream, xb, wt, bias, out);
}

// Round 3
// 462.131 us; speedup vs baseline: 1.0788x; 1.0788x over previous
//
#include <hip/hip_runtime.h>
#include <hip/hip_bf16.h>

// Problem constants (reference: IN_F=4096, OUT_F=4096, GROUP=128, x = (4,2048,4096))
#define K_DIM 4096
#define N_DIM 4096
#define M_DIM 8192
#define NT 64                       // K_DIM / 64 K-tiles

typedef __bf16 bf16x8 __attribute__((ext_vector_type(8)));
typedef float floatx4 __attribute__((ext_vector_type(4)));

__device__ __forceinline__ unsigned short f2bf(float f) {
    union { float f; unsigned u; } v; v.f = f;
    unsigned u = v.u;
    return (unsigned short)((u + 0x7FFFu + ((u >> 16) & 1u)) >> 16);  // RNE
}

// ---------------- kernel 1: cast x (fp32 -> bf16), 8 elems/thread ----------------
__global__ __launch_bounds__(256) void cast_x_kernel(const float* __restrict__ x,
                                                     unsigned short* __restrict__ xb) {
    const int t = blockIdx.x * 256 + threadIdx.x;
    const int base = t * 8;
    float4 f0 = *(const float4*)(x + base);
    float4 f1 = *(const float4*)(x + base + 4);
    int4 o;
    o.x = (int)f2bf(f0.x) | ((int)f2bf(f0.y) << 16);
    o.y = (int)f2bf(f0.z) | ((int)f2bf(f0.w) << 16);
    o.z = (int)f2bf(f1.x) | ((int)f2bf(f1.y) << 16);
    o.w = (int)f2bf(f1.z) | ((int)f2bf(f1.w) << 16);
    *(int4*)(xb + base) = o;
}

// ------------- kernel 2: dequant int4 -> bf16 W^T (N x K, k contiguous), LDS transpose -------------
__global__ __launch_bounds__(256) void dequant_kernel(const int* __restrict__ qw,
                                                      const float* __restrict__ scales,
                                                      const float* __restrict__ zeros,
                                                      unsigned short* __restrict__ wt) {
    __shared__ int4 lds[128 * 8];                   // [n][chunk], 16 KB
    const int tid = threadIdx.x;
    const int nb = (blockIdx.x & 31) * 128;         // n-block base
    const int kb = blockIdx.x >> 5;                 // 0..63, k0 = kb*64
    const int p0 = kb * 8;                          // packed-row base (8 words = 64 k)
    const int g = kb >> 1;                          // quant group (uniform per block)

#pragma unroll
    for (int it = 0; it < 4; ++it) {
        const int w = tid + it * 256;               // 0..1023
        const int p = w >> 7;                       // 0..7
        const int n = w & 127;
        const unsigned word = (unsigned)qw[(p0 + p) * N_DIM + nb + n];
        const float s = scales[g * N_DIM + nb + n];
        const float z = zeros[g * N_DIM + nb + n];
        unsigned short h[8];
#pragma unroll
        for (int j = 0; j < 8; ++j) {
            float q = (float)((word >> (4 * j)) & 0xFu);
            h[j] = f2bf(q * s - z);
        }
        int4 o;
        o.x = (int)h[0] | ((int)h[1] << 16);
        o.y = (int)h[2] | ((int)h[3] << 16);
        o.z = (int)h[4] | ((int)h[5] << 16);
        o.w = (int)h[6] | ((int)h[7] << 16);
        lds[n * 8 + (p ^ (n & 7))] = o;             // swizzled chunk
    }
    __syncthreads();

#pragma unroll
    for (int it = 0; it < 4; ++it) {
        const int r = (tid >> 3) + it * 32;         // n-row 0..127
        const int oc = tid & 7;                     // k-chunk 0..7
        int4 v = lds[r * 8 + (oc ^ (r & 7))];
        *(int4*)(wt + (size_t)(nb + r) * K_DIM + kb * 64 + oc * 8) = v;
    }
}

// ------------- kernel 3: bf16 GEMM, 256x256 tile, BK=64, de-pinned 4-phase counted-vmcnt pipeline --
// A = xb (M x K), B = wt (N x K), C = out (M x N fp32) + bias.
// 8 waves (2M x 4N), each owns 128x64 of C: acc[8][4] f32x4. LDS 128 KiB double-buffered.
// Chunk-XOR swizzle: linear gload_lds dest + pre-swizzled global src; frag reads un-swizzle
// (2 lanes/chunk, verified 0 bank conflicts).
//
// R3 change (de-pinning): REMOVED all sched_barrier(0) and manual lgkmcnt waits — the ds_read->MFMA
// dependency is C-level, so the compiler emits fine-grained partial lgkmcnt waits (m97-style
// 4/3/1/0 laddering): early MFMAs issue as soon as their own fragments land, remaining reads drain
// under the MFMA cluster. Also dropped the mid-phase barrier (4 barriers/K-tile, was 8).
//  P1: read aL(8)+b-lo(4); stage (t+1).A1->obuf; MFMA Q1=Mlo*Nlo; bar
//  P2: read b-hi(4);       stage (t+2).B0->buf;  MFMA Q2=Mlo*Nhi; bar
//  P3: read aH(8, reuse);  stage (t+2).B1->buf;  MFMA Q3=Mhi*Nhi; bar
//  P4:                     stage (t+2).A0->buf;  MFMA Q4=Mhi*Nlo; vmcnt(6); bar
// Staging safety WITHOUT mid-barrier/lgkm0: every read issued in phase P has a consumer MFMA inside
// P's cluster, so a wave reaches the P-end barrier only after all its P reads completed; thus when
// any wave stages region R in a later phase, all waves' reads of R are retired (R's last reads are
// >=1 phase-end barrier earlier: B0 read@P1 staged@P2; B1 read@P2 staged@P3; A0 read@P1 staged@P4;
// obuf.A1 last read@(t-1)P3 staged@P1). vmcnt gating (per-wave, in-order retirement): entering P4
// the queue is [A1(t+1) x2, B0/B1(t+2) x4, A0(t+2) x2 after issue] -> vmcnt(6) retires A1(t+1) and
// everything older => ALL of tile t+1 resident before the P4-end barrier releases P1(t+1) reads.
// Tail: when t+2>=NT stages are skipped -> vmcnt(0) (drains A1(NT-1) at t=NT-2; no-op at t=NT-1).
__device__ __forceinline__ void gl_lds16(const unsigned short* g, unsigned short* l) {
    __builtin_amdgcn_global_load_lds((__attribute__((address_space(1))) void*)g,
                                     (__attribute__((address_space(3))) void*)l, 16, 0, 0);
}

__global__ __launch_bounds__(512, 2) void gemm_kernel(const unsigned short* __restrict__ A,
                                                      const unsigned short* __restrict__ B,
                                                      const float* __restrict__ bias,
                                                      float* __restrict__ C) {
    __shared__ unsigned short As[2 * 256 * 64];     // 64 KB
    __shared__ unsigned short Bs[2 * 256 * 64];     // 64 KB

    const int tid = threadIdx.x;
    const int lane = tid & 63;
    const int wave = tid >> 6;

    // XCD-aware swizzle (512 blocks, 512 % 8 == 0 -> bijective)
    int bid = blockIdx.x;
    bid = (bid & 7) * 64 + (bid >> 3);
    const int tileM = (bid >> 4) * 256;
    const int tileN = (bid & 15) * 256;

    const int m0 = (wave >> 2) * 128;               // wave's M offset within tile
    const int n0 = (wave & 3) * 64;                 // wave's N offset within tile
    const int frow = lane & 15;
    const int fkq = lane >> 4;                      // k-chunk quarter
    const int sw = frow & 7;
    const int ch0 = (fkq ^ sw) << 3;                // kh=0 un-swizzled elem offset
    const int ch1 = ((fkq ^ sw) ^ 4) << 3;          // kh=1

    // staging geometry: thread covers one 16B chunk per half-tile load
    const int r0 = tid >> 3;                        // 0..63
    const int kcg = (tid & 7) ^ (r0 & 7);
    const int dst0 = tid * 8;                       // elem offset in half (load 0); load 1: +4096

    const unsigned short* Abase = A + (size_t)(tileM + r0) * K_DIM + kcg * 8;
    const unsigned short* Bbase = B + (size_t)(tileN + r0) * K_DIM + kcg * 8;

#define STAGE_A(T, H, BUF) do {                                                        \
        const unsigned short* _s = Abase + (size_t)(H) * (128 * K_DIM) + (T) * 64;     \
        gl_lds16(_s, &As[((BUF) << 14) + ((H) << 13) + dst0]);                         \
        gl_lds16(_s + 64 * K_DIM, &As[((BUF) << 14) + ((H) << 13) + 4096 + dst0]);     \
    } while (0)
#define STAGE_B(T, H, BUF) do {                                                        \
        const unsigned short* _s = Bbase + (size_t)(H) * (128 * K_DIM) + (T) * 64;     \
        gl_lds16(_s, &Bs[((BUF) << 14) + ((H) << 13) + dst0]);                         \
        gl_lds16(_s + 64 * K_DIM, &Bs[((BUF) << 14) + ((H) << 13) + 4096 + dst0]);     \
    } while (0)

    floatx4 acc[8][4];
#pragma unroll
    for (int i = 0; i < 8; ++i)
#pragma unroll
        for (int j = 0; j < 4; ++j) acc[i][j] = (floatx4){0.f, 0.f, 0.f, 0.f};

    // prologue: tile0 {B0,B1,A0,A1} -> buf0; tile1 {B0,B1,A0} -> buf1 (7 halves = 14 loads/wave)
    STAGE_B(0, 0, 0); STAGE_B(0, 1, 0); STAGE_A(0, 0, 0); STAGE_A(0, 1, 0);
    STAGE_B(1, 0, 1); STAGE_B(1, 1, 1); STAGE_A(1, 0, 1);
    asm volatile("s_waitcnt vmcnt(6)" ::: "memory");    // tile0's 4 halves retired (in-order)
    __builtin_amdgcn_s_barrier();

    bf16x8 a[4][2], b[4][2];

#pragma unroll 2
    for (int t = 0; t < NT; ++t) {
        const int buf = t & 1;
        const int bo = buf << 14;

        // ---- P1: read aL(8) + b-lo(4); stage (t+1).A1 -> other buf; MFMA Q1 = Mlo x Nlo
#pragma unroll
        for (int mi = 0; mi < 4; ++mi) {
            const int row = m0 + mi * 16 + frow;
            a[mi][0] = *(const bf16x8*)&As[bo + row * 64 + ch0];
            a[mi][1] = *(const bf16x8*)&As[bo + row * 64 + ch1];
        }
#pragma unroll
        for (int ni = 0; ni < 2; ++ni) {
            const int row = n0 + ni * 16 + frow;
            b[ni][0] = *(const bf16x8*)&Bs[bo + row * 64 + ch0];
            b[ni][1] = *(const bf16x8*)&Bs[bo + row * 64 + ch1];
        }
        if (t + 1 < NT) STAGE_A(t + 1, 1, buf ^ 1);
        __builtin_amdgcn_s_setprio(1);
#pragma unroll
        for (int mi = 0; mi < 4; ++mi)
#pragma unroll
            for (int ni = 0; ni < 2; ++ni)
#pragma unroll
                for (int kh = 0; kh < 2; ++kh)
                    acc[mi][ni] = __builtin_amdgcn_mfma_f32_16x16x32_bf16(
                        a[mi][kh], b[ni][kh], acc[mi][ni], 0, 0, 0);
        __builtin_amdgcn_s_setprio(0);
        __builtin_amdgcn_s_barrier();

        // ---- P2: read b-hi(4); stage (t+2).B0 -> this buf; MFMA Q2 = Mlo x Nhi
#pragma unroll
        for (int ni = 2; ni < 4; ++ni) {
            const int row = n0 + ni * 16 + frow;
            b[ni][0] = *(const bf16x8*)&Bs[bo + row * 64 + ch0];
            b[ni][1] = *(const bf16x8*)&Bs[bo + row * 64 + ch1];
        }
        if (t + 2 < NT) STAGE_B(t + 2, 0, buf);
        __builtin_amdgcn_s_setprio(1);
#pragma unroll
        for (int mi = 0; mi < 4; ++mi)
#pragma unroll
            for (int ni = 2; ni < 4; ++ni)
#pragma unroll
                for (int kh = 0; kh < 2; ++kh)
                    acc[mi][ni] = __builtin_amdgcn_mfma_f32_16x16x32_bf16(
                        a[mi][kh], b[ni][kh], acc[mi][ni], 0, 0, 0);
        __builtin_amdgcn_s_setprio(0);
        __builtin_amdgcn_s_barrier();

        // ---- P3: read aH(8, reuse a[] regs); stage (t+2).B1 -> this buf; MFMA Q3 = Mhi x Nhi
#pragma unroll
        for (int mi = 0; mi < 4; ++mi) {
            const int row = m0 + 64 + mi * 16 + frow;
            a[mi][0] = *(const bf16x8*)&As[bo + row * 64 + ch0];
            a[mi][1] = *(const bf16x8*)&As[bo + row * 64 + ch1];
        }
        if (t + 2 < NT) STAGE_B(t + 2, 1, buf);
        __builtin_amdgcn_s_setprio(1);
#pragma unroll
        for (int mi = 0; mi < 4; ++mi)
#pragma unroll
            for (int ni = 2; ni < 4; ++ni)
#pragma unroll
                for (int kh = 0; kh < 2; ++kh)
                    acc[4 + mi][ni] = __builtin_amdgcn_mfma_f32_16x16x32_bf16(
                        a[mi][kh], b[ni][kh], acc[4 + mi][ni], 0, 0, 0);
        __builtin_amdgcn_s_setprio(0);
        __builtin_amdgcn_s_barrier();

        // ---- P4: stage (t+2).A0 -> this buf; MFMA Q4 = Mhi x Nlo; counted vmcnt drain
        if (t + 2 < NT) STAGE_A(t + 2, 0, buf);
        __builtin_amdgcn_s_setprio(1);
#pragma unroll
        for (int mi = 0; mi < 4; ++mi)
#pragma unroll
            for (int ni = 0; ni < 2; ++ni)
#pragma unroll
                for (int kh = 0; kh < 2; ++kh)
                    acc[4 + mi][ni] = __builtin_amdgcn_mfma_f32_16x16x32_bf16(
                        a[mi][kh], b[ni][kh], acc[4 + mi][ni], 0, 0, 0);
        __builtin_amdgcn_s_setprio(0);
        // counted drain: 3 half-tiles (t+2) stay in flight; tile t+1 guaranteed landed for all
        // waves after the following barrier.
        if (t + 2 < NT) { asm volatile("s_waitcnt vmcnt(6)" ::: "memory"); }
        else            { asm volatile("s_waitcnt vmcnt(0)" ::: "memory"); }
        __builtin_amdgcn_s_barrier();
    }
#undef STAGE_A
#undef STAGE_B

    // no pending LDS-DMA may outlive the kernel (no-op: last iteration drained vmcnt(0))
    asm volatile("s_waitcnt vmcnt(0)" ::: "memory");

    // epilogue: C/D layout col = lane&15, row = (lane>>4)*4 + reg
    const int crow = (lane >> 4) * 4;
    const int ccol = lane & 15;
#pragma unroll
    for (int ni = 0; ni < 4; ++ni) {
        const int gcol = tileN + n0 + ni * 16 + ccol;
        const float bv = bias[gcol];
#pragma unroll
        for (int mi = 0; mi < 8; ++mi) {
            const int rbase = (tileM + m0 + mi * 16 + crow) * N_DIM + gcol;
#pragma unroll
            for (int r = 0; r < 4; ++r)
                C[rbase + r * N_DIM] = acc[mi][ni][r] + bv;
        }
    }
}

extern "C" void kernel_launch(void* const* d_in, const int* in_sizes, int n_in,
                              void* d_out, int out_size, void* d_ws, size_t ws_size,
                              hipStream_t stream) {
    (void)in_sizes; (void)n_in; (void)out_size; (void)ws_size;
    const float* x      = (const float*)d_in[0];
    const int*   qw     = (const int*)d_in[1];
    const float* scales = (const float*)d_in[2];
    const float* zeros  = (const float*)d_in[3];
    const float* bias   = (const float*)d_in[4];
    float* out = (float*)d_out;

    unsigned short* xb = (unsigned short*)d_ws;                      // 8192*4096 bf16 = 64 MiB
    unsigned short* wt = xb + (size_t)M_DIM * K_DIM;                 // 4096*4096 bf16 = 32 MiB

    hipLaunchKernelGGL(cast_x_kernel, dim3(16384), dim3(256), 0, stream, x, xb);
    hipLaunchKernelGGL(dequant_kernel, dim3(2048), dim3(256), 0, stream, qw, scales, zeros, wt);
    hipLaunchKernelGGL(gemm_kernel, dim3(512), dim3(512), 0, stream, xb, wt, bias, out);
}